// Round 5
// baseline (90.812 us; speedup 1.0000x reference)
//
#include <hip/hip_runtime.h>

#define BB 8
#define CC 256
#define HH 96
#define WW 96
#define HWW (HH*WW)
#define NLOC 256        // local prototypes (MFMA path)
#define PPAD 257        // + global prototype
#define THRESH 0.95f
#define NORM_EPS 1e-4f

typedef __attribute__((ext_vector_type(8))) short bf16x8;
typedef __attribute__((ext_vector_type(4))) float f32x4;

// ---- fused kernel 0+1: mask pooling (8 blocks) + feature pooling (2048) ----
__global__ void k01(const float* __restrict__ sup_fts,
                    const float* __restrict__ sup_mask,
                    const float* __restrict__ true_bg,
                    float* __restrict__ protos,
                    float* __restrict__ validf,
                    float* __restrict__ masksum) {
    __shared__ float red[256];
    int blk = blockIdx.x;
    int t = threadIdx.x;
    if (blk < BB * CC) {
        // ---- k1: avg-pool sup_fts + masked sums (gproto numerator) ----
        int b = blk >> 8, c = blk & 255;
        int gy = t >> 4, gx = t & 15;
        const float* fb = sup_fts + ((size_t)b * CC + c) * HWW;
        const float* mb = sup_mask + (size_t)b * HWW;
        int base = gy * 6 * WW + gx * 6;
        float fs = 0.f, fm = 0.f;
        for (int r = 0; r < 6; ++r) {
            const float* rowf = fb + base + r * WW;
            const float* rowm = mb + base + r * WW;
#pragma unroll
            for (int h = 0; h < 3; ++h) {
                float2 v  = *(const float2*)(rowf + 2 * h);
                float2 mk = *(const float2*)(rowm + 2 * h);
                fs += v.x + v.y;
                fm = fmaf(v.x, mk.x, fm);
                fm = fmaf(v.y, mk.y, fm);
            }
        }
        protos[((size_t)b * PPAD + t) * CC + c] = fs * (1.f / 36.f);
        red[t] = fm;
        __syncthreads();
        for (int off = 128; off > 0; off >>= 1) {
            if (t < off) red[t] += red[t + off];
            __syncthreads();
        }
        if (t == 0) protos[((size_t)b * PPAD + 256) * CC + c] = red[0];
    } else {
        // ---- k0: pooled masks -> valid flags + mask sum ----
        int b = blk - BB * CC;
        int gy = t >> 4, gx = t & 15;
        const float* mb = sup_mask + (size_t)b * HWW;
        const float* gb = true_bg  + (size_t)b * HWW;
        int base = gy * 6 * WW + gx * 6;
        float ms = 0.f, bs = 0.f;
        for (int r = 0; r < 6; ++r) {
            const float* rowm = mb + base + r * WW;
            const float* rowg = gb + base + r * WW;
#pragma unroll
            for (int h = 0; h < 3; ++h) {
                float2 mk = *(const float2*)(rowm + 2 * h);
                float2 bg2 = *(const float2*)(rowg + 2 * h);
                ms += mk.x + mk.y;
                bs += bg2.x + bg2.y;
            }
        }
        float mmean = ms * (1.f / 36.f);
        float bmean = bs * (1.f / 36.f);
        validf[b * PPAD + t] = (mmean > THRESH && bmean < 0.5f) ? 1.f : 0.f;
        if (t == 0) validf[b * PPAD + 256] = 1.f;
        red[t] = ms;
        __syncthreads();
        for (int off = 128; off > 0; off >>= 1) {
            if (t < off) red[t] += red[t + off];
            __syncthreads();
        }
        if (t == 0) masksum[b] = red[0];
    }
}

// ------- kernel 2: finish gproto + normalize + emit bf16 hi/lo B-image ------
// Bimg layout (ushorts): [B][8 kc][2 hilo][256 p][32 j]  — 64B rows, compact
__global__ void k2_norm(float* __restrict__ protos,
                        const float* __restrict__ masksum,
                        unsigned short* __restrict__ Bimg) {
    int bp = blockIdx.x;
    int b = bp / PPAD;
    int p = bp - b * PPAD;
    int t = threadIdx.x;            // channel
    float v = protos[((size_t)b * PPAD + p) * CC + t];
    if (p == 256) v = v / (masksum[b] + 1e-5f);
    __shared__ float red[256];
    red[t] = v * v;
    __syncthreads();
    for (int off = 128; off > 0; off >>= 1) {
        if (t < off) red[t] += red[t + off];
        __syncthreads();
    }
    float norm = sqrtf(red[0]);
    float vn = v / fmaxf(norm, NORM_EPS);
    protos[((size_t)b * PPAD + p) * CC + t] = vn;
    if (p < NLOC) {
        unsigned int u = __float_as_uint(vn);
        unsigned short hi = (unsigned short)(u >> 16);          // truncation
        float lo = vn - __uint_as_float(u & 0xffff0000u);       // exact
        unsigned int ul = __float_as_uint(lo);
        unsigned short lob = (unsigned short)((ul + 0x7fffu + ((ul >> 16) & 1u)) >> 16); // RNE
        int kc = t >> 5, j = t & 31;
        size_t base = ((size_t)(b * 8 + kc) * 2) * 8192;
        Bimg[base + (size_t)p * 32 + j] = hi;                   // hilo=0
        Bimg[base + 8192 + (size_t)p * 32 + j] = lob;           // hilo=1
    }
}

// ---------------- kernel 3: MFMA dists + masked softmax + weighted sum ------
// 1-wave blocks (64 thr), 32 px each, all 256 protos. NO LDS, NO barriers.
// B-frags stream from L2 (256KB/batch, XCD-affine via b=blk&7); register
// double-buffer 2 coltiles deep; q(kc+1) prefetched a full kc ahead.

#define LOADB(BHx, BLx, KC, T0)                                              \
    {                                                                        \
        const unsigned short* p0 = Bb + (size_t)(KC) * 16384 +               \
                                   ((T0) * 16 + n) * 32 + g * 8;             \
        BHx[0] = *(const bf16x8*)(p0);                                       \
        BHx[1] = *(const bf16x8*)(p0 + 512);                                 \
        BLx[0] = *(const bf16x8*)(p0 + 8192);                                \
        BLx[1] = *(const bf16x8*)(p0 + 8704);                                \
    }

#define MFMA2(BHx, BLx, T0)                                                  \
    {                                                                        \
        _Pragma("unroll")                                                    \
        for (int u = 0; u < 2; ++u) {                                        \
            _Pragma("unroll")                                                \
            for (int sub = 0; sub < 2; ++sub) {                              \
                acc[sub][(T0) + u] = __builtin_amdgcn_mfma_f32_16x16x32_bf16(\
                    AH[sub], BHx[u], acc[sub][(T0) + u], 0, 0, 0);           \
                acc[sub][(T0) + u] = __builtin_amdgcn_mfma_f32_16x16x32_bf16(\
                    AL[sub], BHx[u], acc[sub][(T0) + u], 0, 0, 0);           \
                acc[sub][(T0) + u] = __builtin_amdgcn_mfma_f32_16x16x32_bf16(\
                    AH[sub], BLx[u], acc[sub][(T0) + u], 0, 0, 0);           \
            }                                                                \
        }                                                                    \
    }

__global__ __launch_bounds__(64)
void k3_mfma(const float* __restrict__ qry,
             const unsigned short* __restrict__ Bimg,
             const float* __restrict__ protos_n,
             const float* __restrict__ validf,
             float* __restrict__ out) {
    int blk = blockIdx.x;
    int b = blk & 7;              // batch <-> XCD affinity (round-robin heuristic)
    int tile = blk >> 3;          // 0..287
    int lane = threadIdx.x;
    int g = lane >> 4;            // k-group
    int n = lane & 15;            // proto-col lane / pixel lane
    int px0 = tile * 32;

    const float* qb = qry + (size_t)b * CC * HWW;
    const float* gp = protos_n + ((size_t)b * PPAD + 256) * CC;
    const unsigned short* Bb = Bimg + (size_t)b * 8 * 2 * 8192;

    f32x4 acc[2][16];
#pragma unroll
    for (int sub = 0; sub < 2; ++sub)
#pragma unroll
        for (int tt = 0; tt < 16; ++tt)
            acc[sub][tt] = (f32x4){0.f, 0.f, 0.f, 0.f};
    float norm2[2] = {0.f, 0.f};
    float gacc[2] = {0.f, 0.f};
    float qnext[2][8];
    float gpvn[8];
    bf16x8 AH[2], AL[2];
    bf16x8 BH0[2], BL0[2], BH1[2], BL1[2];

    auto QLOADN = [&](int kc) {
        int c0 = kc * 32;
#pragma unroll
        for (int sub = 0; sub < 2; ++sub) {
            const float* qcol = qb + (size_t)(c0 + 8 * g) * HWW + (px0 + sub * 16 + n);
#pragma unroll
            for (int j = 0; j < 8; ++j) qnext[sub][j] = qcol[(size_t)j * HWW];
        }
#pragma unroll
        for (int j = 0; j < 8; ++j) gpvn[j] = gp[c0 + 8 * g + j];
    };

    auto SPLITN = [&]() {   // qnext -> AH/AL; accumulate norm2, gacc
#pragma unroll
        for (int sub = 0; sub < 2; ++sub) {
            union { bf16x8 v; unsigned int u[4]; } H, L;
#pragma unroll
            for (int jp = 0; jp < 4; ++jp) {
                unsigned int u0 = __float_as_uint(qnext[sub][2 * jp]);
                unsigned int u1 = __float_as_uint(qnext[sub][2 * jp + 1]);
                H.u[jp] = (u0 >> 16) | (u1 & 0xffff0000u);
                float lo0 = qnext[sub][2 * jp]     - __uint_as_float(u0 & 0xffff0000u);
                float lo1 = qnext[sub][2 * jp + 1] - __uint_as_float(u1 & 0xffff0000u);
                unsigned int r0 = __float_as_uint(lo0);
                unsigned int r1 = __float_as_uint(lo1);
                r0 = (r0 + 0x7fffu + ((r0 >> 16) & 1u)) >> 16;
                r1 = (r1 + 0x7fffu + ((r1 >> 16) & 1u)) & 0xffff0000u;
                L.u[jp] = r0 | r1;
            }
            AH[sub] = H.v; AL[sub] = L.v;
#pragma unroll
            for (int j = 0; j < 8; ++j) {
                norm2[sub] = fmaf(qnext[sub][j], qnext[sub][j], norm2[sub]);
                gacc[sub]  = fmaf(qnext[sub][j], gpvn[j], gacc[sub]);
            }
        }
    };

    // ---- prologue: q(0) + first B coltile pair ----
    QLOADN(0);
    LOADB(BH0, BL0, 0, 0);
    SPLITN();

    // ---- main loop: 8 kc x 16 coltiles, reg-dbuf 2 coltiles deep ----
    for (int kc = 0; kc < 8; ++kc) {
        LOADB(BH1, BL1, kc, 2);
        if (kc < 7) QLOADN(kc + 1);          // q prefetch ~1 full kc ahead
        MFMA2(BH0, BL0, 0);
        LOADB(BH0, BL0, kc, 4);
        MFMA2(BH1, BL1, 2);
        LOADB(BH1, BL1, kc, 6);
        MFMA2(BH0, BL0, 4);
        LOADB(BH0, BL0, kc, 8);
        MFMA2(BH1, BL1, 6);
        LOADB(BH1, BL1, kc, 10);
        MFMA2(BH0, BL0, 8);
        LOADB(BH0, BL0, kc, 12);
        MFMA2(BH1, BL1, 10);
        LOADB(BH1, BL1, kc, 14);
        MFMA2(BH0, BL0, 12);
        if (kc < 7) LOADB(BH0, BL0, kc + 1, 0);
        MFMA2(BH1, BL1, 14);
        if (kc < 7) SPLITN();                // consume q(kc+1), set A-frags
    }

    // ---- reduce |q|^2 and g-dot over k-groups (lanes n, n+16, n+32, n+48) --
#pragma unroll
    for (int sub = 0; sub < 2; ++sub) {
        norm2[sub] += __shfl_xor(norm2[sub], 16);
        norm2[sub] += __shfl_xor(norm2[sub], 32);
        gacc[sub]  += __shfl_xor(gacc[sub], 16);
        gacc[sub]  += __shfl_xor(gacc[sub], 32);
    }

    // per-row (px = px0 + sub*16 + 4g + r) norm & global-proto dist
    float rnorm[2][4], gd[2][4];
#pragma unroll
    for (int sub = 0; sub < 2; ++sub)
#pragma unroll
        for (int r = 0; r < 4; ++r) {
            float n2 = __shfl(norm2[sub], 4 * g + r);
            float rn = 1.f / fmaxf(sqrtf(n2), NORM_EPS);
            rnorm[sub][r] = rn;
            gd[sub][r] = __shfl(gacc[sub], 4 * g + r) * rn;
        }

    // valid flags for this lane's proto column across the 16 tiles
    float vf[16];
    const float* vb = validf + b * PPAD;
#pragma unroll
    for (int tt = 0; tt < 16; ++tt) vf[tt] = vb[tt * 16 + n];

    // ---- softmax (fixed shift 1.1, cosines bounded) + weighted sum ----
    // global-proto term added ONCE per pixel AFTER the 16-lane reduction.
#pragma unroll
    for (int sub = 0; sub < 2; ++sub) {
        float S[4] = {0.f, 0.f, 0.f, 0.f};
        float NN[4] = {0.f, 0.f, 0.f, 0.f};
#pragma unroll
        for (int tt = 0; tt < 16; ++tt) {
#pragma unroll
            for (int r = 0; r < 4; ++r) {
                float d = acc[sub][tt][r] * rnorm[sub][r];
                float l = (vf[tt] != 0.f) ? d : -1e30f;
                float e = __expf(l - 1.1f);          // underflows to exactly 0 when masked
                S[r] += e;
                NN[r] = fmaf(e, l, NN[r]);
            }
        }
#pragma unroll
        for (int r = 0; r < 4; ++r) {
#pragma unroll
            for (int m = 1; m < 16; m <<= 1) {
                S[r]  += __shfl_xor(S[r], m);
                NN[r] += __shfl_xor(NN[r], m);
            }
            float eg = __expf(gd[sub][r] - 1.1f);    // global proto, exactly once
            S[r] += eg;
            NN[r] = fmaf(eg, gd[sub][r], NN[r]);
        }
        if (n < 4) {   // lane (g, n<4) writes row 4g+n, slot r=n
            float Ssel = (n == 0) ? S[0] : (n == 1) ? S[1] : (n == 2) ? S[2] : S[3];
            float Nsel = (n == 0) ? NN[0] : (n == 1) ? NN[1] : (n == 2) ? NN[2] : NN[3];
            out[(size_t)b * HWW + px0 + sub * 16 + 4 * g + n] = Nsel / Ssel;
        }
    }
}

extern "C" void kernel_launch(void* const* d_in, const int* in_sizes, int n_in,
                              void* d_out, int out_size, void* d_ws, size_t ws_size,
                              hipStream_t stream) {
    const float* qry = (const float*)d_in[0];
    const float* sup = (const float*)d_in[1];
    const float* msk = (const float*)d_in[2];
    const float* bg  = (const float*)d_in[3];
    float* out = (float*)d_out;

    float* ws = (float*)d_ws;
    float* protos  = ws;                                   // [B][257][256] f32
    float* validf  = protos + (size_t)BB * PPAD * CC;      // [B][257]
    float* masksum = validf + (size_t)BB * PPAD;           // [B]
    unsigned short* Bimg = (unsigned short*)(masksum + BB); // [B][8][2][256][32] ushorts

    hipLaunchKernelGGL(k01, dim3(BB * CC + BB), dim3(256), 0, stream,
                       sup, msk, bg, protos, validf, masksum);
    hipLaunchKernelGGL(k2_norm, dim3(BB * PPAD), dim3(256), 0, stream, protos, masksum, Bimg);
    hipLaunchKernelGGL(k3_mfma, dim3(BB * (HWW / 32)), dim3(64), 0, stream,
                       qry, Bimg, protos, validf, out);
}

// Round 6
// 71.588 us; speedup vs baseline: 1.2685x; 1.2685x over previous
//
#include <hip/hip_runtime.h>

#define BB 8
#define CC 256
#define HH 96
#define WW 96
#define HWW (HH*WW)
#define NLOC 256        // local prototypes (MFMA path)
#define PPAD 257        // + global prototype
#define THRESH 0.95f
#define NORM_EPS 1e-4f

typedef __attribute__((ext_vector_type(8))) short bf16x8;
typedef __attribute__((ext_vector_type(4))) float f32x4;

// ---- fused kernel 0+1: mask pooling (8 blocks) + feature pooling (2048) ----
__global__ void k01(const float* __restrict__ sup_fts,
                    const float* __restrict__ sup_mask,
                    const float* __restrict__ true_bg,
                    float* __restrict__ protos,
                    float* __restrict__ validf,
                    float* __restrict__ masksum) {
    __shared__ float red[256];
    int blk = blockIdx.x;
    int t = threadIdx.x;
    if (blk < BB * CC) {
        int b = blk >> 8, c = blk & 255;
        int gy = t >> 4, gx = t & 15;
        const float* fb = sup_fts + ((size_t)b * CC + c) * HWW;
        const float* mb = sup_mask + (size_t)b * HWW;
        int base = gy * 6 * WW + gx * 6;
        float fs = 0.f, fm = 0.f;
        for (int r = 0; r < 6; ++r) {
            const float* rowf = fb + base + r * WW;
            const float* rowm = mb + base + r * WW;
#pragma unroll
            for (int h = 0; h < 3; ++h) {
                float2 v  = *(const float2*)(rowf + 2 * h);
                float2 mk = *(const float2*)(rowm + 2 * h);
                fs += v.x + v.y;
                fm = fmaf(v.x, mk.x, fm);
                fm = fmaf(v.y, mk.y, fm);
            }
        }
        protos[((size_t)b * PPAD + t) * CC + c] = fs * (1.f / 36.f);
        red[t] = fm;
        __syncthreads();
        for (int off = 128; off > 0; off >>= 1) {
            if (t < off) red[t] += red[t + off];
            __syncthreads();
        }
        if (t == 0) protos[((size_t)b * PPAD + 256) * CC + c] = red[0];
    } else {
        int b = blk - BB * CC;
        int gy = t >> 4, gx = t & 15;
        const float* mb = sup_mask + (size_t)b * HWW;
        const float* gb = true_bg  + (size_t)b * HWW;
        int base = gy * 6 * WW + gx * 6;
        float ms = 0.f, bs = 0.f;
        for (int r = 0; r < 6; ++r) {
            const float* rowm = mb + base + r * WW;
            const float* rowg = gb + base + r * WW;
#pragma unroll
            for (int h = 0; h < 3; ++h) {
                float2 mk = *(const float2*)(rowm + 2 * h);
                float2 bg2 = *(const float2*)(rowg + 2 * h);
                ms += mk.x + mk.y;
                bs += bg2.x + bg2.y;
            }
        }
        float mmean = ms * (1.f / 36.f);
        float bmean = bs * (1.f / 36.f);
        validf[b * PPAD + t] = (mmean > THRESH && bmean < 0.5f) ? 1.f : 0.f;
        if (t == 0) validf[b * PPAD + 256] = 1.f;
        red[t] = ms;
        __syncthreads();
        for (int off = 128; off > 0; off >>= 1) {
            if (t < off) red[t] += red[t + off];
            __syncthreads();
        }
        if (t == 0) masksum[b] = red[0];
    }
}

// ------- kernel 2: finish gproto + normalize + emit bf16 hi/lo B-image ------
// Bimg layout (ushorts): [B][8 kc][2 hilo][256 p][32 j]  — 64B rows, compact
__global__ void k2_norm(float* __restrict__ protos,
                        const float* __restrict__ masksum,
                        unsigned short* __restrict__ Bimg) {
    int bp = blockIdx.x;
    int b = bp / PPAD;
    int p = bp - b * PPAD;
    int t = threadIdx.x;            // channel
    float v = protos[((size_t)b * PPAD + p) * CC + t];
    if (p == 256) v = v / (masksum[b] + 1e-5f);
    __shared__ float red[256];
    red[t] = v * v;
    __syncthreads();
    for (int off = 128; off > 0; off >>= 1) {
        if (t < off) red[t] += red[t + off];
        __syncthreads();
    }
    float norm = sqrtf(red[0]);
    float vn = v / fmaxf(norm, NORM_EPS);
    protos[((size_t)b * PPAD + p) * CC + t] = vn;
    if (p < NLOC) {
        unsigned int u = __float_as_uint(vn);
        unsigned short hi = (unsigned short)(u >> 16);          // truncation
        float lo = vn - __uint_as_float(u & 0xffff0000u);       // exact
        unsigned int ul = __float_as_uint(lo);
        unsigned short lob = (unsigned short)((ul + 0x7fffu + ((ul >> 16) & 1u)) >> 16); // RNE
        int kc = t >> 5, j = t & 31;
        size_t base = ((size_t)(b * 8 + kc) * 2) * 8192;
        Bimg[base + (size_t)p * 32 + j] = hi;                   // hilo=0
        Bimg[base + 8192 + (size_t)p * 32 + j] = lob;           // hilo=1
    }
}

// ---------------- kernel 3: MFMA dists + masked softmax + weighted sum ------
// Block = 512 thr = 8 waves, 64 px/block. Wave w owns protos [32w, 32w+32),
// ALL 64 px. A (q hi/lo bf16) split-staged in LDS, double-buffered, shared by
// all waves; B streamed L2 -> registers with counted vmcnt (NO global_load_lds
// -> barriers drain lgkmcnt only). Fixed-shift softmax => cross-wave merge is
// a plain S/N sum via LDS. |q|^2 and gproto dot computed by staging threads
// in fp32. Grid 1152 (4.5 blk/CU), ~16 waves/CU resident.
__global__ __launch_bounds__(512, 4)
void k3_mfma(const float* __restrict__ qry,
             const unsigned short* __restrict__ Bimg,
             const float* __restrict__ protos_n,
             const float* __restrict__ validf,
             float* __restrict__ out) {
    __shared__ unsigned short Albuf[2][2][2560];   // [buf][hi/lo][64px * 40pad] = 20 KB
    __shared__ float nrm_l[8][64], gac_l[8][64];   // staging partials
    __shared__ float S_l[8][64], N_l[8][64];       // per-wave softmax partials
    __shared__ float rn_s[64], gd_s[64];

    int bid = blockIdx.x;
    int b = bid / 144;
    int tile = bid - b * 144;
    int t = threadIdx.x;              // 0..511
    int lane = t & 63;
    int w = t >> 6;                   // wave 0..7
    int g = lane >> 4;                // k-group
    int n = lane & 15;                // 16-dim lane (px for A-frag, proto for B-frag)
    int px0 = tile * 64;

    int spx = t & 63;                 // staging: pixel owned by this thread
    int k4 = (t >> 6) * 4;            // staging: k-quad within the 32-k chunk

    const float* qb = qry + (size_t)b * CC * HWW;
    const float* gp = protos_n + ((size_t)b * PPAD + 256) * CC;
    const unsigned short* Bb = Bimg + (size_t)b * 8 * 2 * 8192;

    f32x4 acc[4][2];                  // [px-sub][ct]: 64px x 32 protos
#pragma unroll
    for (int s = 0; s < 4; ++s)
#pragma unroll
        for (int c = 0; c < 2; ++c) acc[s][c] = (f32x4){0.f, 0.f, 0.f, 0.f};

    float nrm = 0.f, gac = 0.f;
    float qs[2][4], gpv[2][4];
    bf16x8 BH[2][2], BL[2][2];        // [buf][ct]

#define QLOADN(KC, QP)                                                        \
    {                                                                         \
        int c0 = (KC) * 32 + k4;                                              \
        _Pragma("unroll")                                                     \
        for (int j = 0; j < 4; ++j) {                                         \
            qs[QP][j]  = qb[(size_t)(c0 + j) * HWW + px0 + spx];              \
            gpv[QP][j] = gp[c0 + j];                                          \
        }                                                                     \
    }

#define LOADB(KC, BUF)                                                        \
    {                                                                         \
        _Pragma("unroll")                                                     \
        for (int ct = 0; ct < 2; ++ct) {                                      \
            const unsigned short* p0 = Bb + (size_t)(KC) * 16384 +            \
                                       (w * 32 + ct * 16 + n) * 32 + g * 8;   \
            BH[BUF][ct] = *(const bf16x8*)(p0);                               \
            BL[BUF][ct] = *(const bf16x8*)(p0 + 8192);                        \
        }                                                                     \
    }

#define SPLITW(QP, BUF)                                                       \
    {                                                                         \
        unsigned int hh[4], ll[4];                                            \
        _Pragma("unroll")                                                     \
        for (int j = 0; j < 4; ++j) {                                         \
            float qv = qs[QP][j];                                             \
            unsigned int u = __float_as_uint(qv);                             \
            hh[j] = u >> 16;                                                  \
            float lof = qv - __uint_as_float(u & 0xffff0000u);                \
            unsigned int ul = __float_as_uint(lof);                           \
            ll[j] = (ul + 0x7fffu + ((ul >> 16) & 1u)) >> 16;                 \
            nrm = fmaf(qv, qv, nrm);                                          \
            gac = fmaf(qv, gpv[QP][j], gac);                                  \
        }                                                                     \
        uint2 Hp, Lp;                                                         \
        Hp.x = hh[0] | (hh[1] << 16); Hp.y = hh[2] | (hh[3] << 16);           \
        Lp.x = ll[0] | (ll[1] << 16); Lp.y = ll[2] | (ll[3] << 16);           \
        *(uint2*)&Albuf[BUF][0][spx * 40 + k4] = Hp;                          \
        *(uint2*)&Albuf[BUF][1][spx * 40 + k4] = Lp;                          \
    }

    // ---- prologue: B(0) oldest, then q(0); B(1), q(1); split(0) ----
    LOADB(0, 0);
    QLOADN(0, 0);
    LOADB(1, 1);
    QLOADN(1, 1);
    SPLITW(0, 0);                     // waits q(0) via counted vmcnt
    __syncthreads();                  // A(0) visible

    // ---- main loop (fully unrolled; 1 barrier per kc, lgkm-only drains) ----
#pragma unroll
    for (int kc = 0; kc < 8; ++kc) {
        if (kc < 6) QLOADN(kc + 2, kc & 1);      // q 2-kc lookahead
#pragma unroll
        for (int sub = 0; sub < 4; ++sub) {
            bf16x8 AHf = *(const bf16x8*)&Albuf[kc & 1][0][(sub * 16 + n) * 40 + g * 8];
            bf16x8 ALf = *(const bf16x8*)&Albuf[kc & 1][1][(sub * 16 + n) * 40 + g * 8];
#pragma unroll
            for (int ct = 0; ct < 2; ++ct) {
                acc[sub][ct] = __builtin_amdgcn_mfma_f32_16x16x32_bf16(AHf, BH[kc & 1][ct], acc[sub][ct], 0, 0, 0);
                acc[sub][ct] = __builtin_amdgcn_mfma_f32_16x16x32_bf16(ALf, BH[kc & 1][ct], acc[sub][ct], 0, 0, 0);
                acc[sub][ct] = __builtin_amdgcn_mfma_f32_16x16x32_bf16(AHf, BL[kc & 1][ct], acc[sub][ct], 0, 0, 0);
            }
        }
        if (kc < 6) LOADB(kc + 2, kc & 1);       // refill B buf just consumed
        if (kc < 7) {
            SPLITW((kc + 1) & 1, (kc + 1) & 1);  // q(kc+1) -> A lds (other buf)
            __syncthreads();
        }
    }

    // ---- reduce |q|^2 and gproto dot (staging-thread partials) ----
    nrm_l[w][spx] = nrm;
    gac_l[w][spx] = gac;
    __syncthreads();
    if (t < 64) {
        float n2 = 0.f, gs = 0.f;
#pragma unroll
        for (int i = 0; i < 8; ++i) { n2 += nrm_l[i][t]; gs += gac_l[i][t]; }
        float rn = 1.f / fmaxf(sqrtf(n2), NORM_EPS);
        rn_s[t] = rn;
        gd_s[t] = gs * rn;
    }
    __syncthreads();

    // ---- per-wave softmax partials (fixed shift 1.1; 32 protos/wave) ----
    float vf0 = validf[b * PPAD + w * 32 + n];
    float vf1 = validf[b * PPAD + w * 32 + 16 + n];
#pragma unroll
    for (int sub = 0; sub < 4; ++sub) {
#pragma unroll
        for (int r = 0; r < 4; ++r) {
            int px = sub * 16 + 4 * g + r;
            float rnv = rn_s[px];                 // broadcast read
            float d0 = acc[sub][0][r] * rnv;
            float d1 = acc[sub][1][r] * rnv;
            float l0 = (vf0 != 0.f) ? d0 : -1e30f;
            float l1 = (vf1 != 0.f) ? d1 : -1e30f;
            float e0 = __expf(l0 - 1.1f);
            float e1 = __expf(l1 - 1.1f);
            float s = e0 + e1;
            float nn = fmaf(e0, l0, e1 * l1);
#pragma unroll
            for (int m = 1; m < 16; m <<= 1) {
                s  += __shfl_xor(s, m);
                nn += __shfl_xor(nn, m);
            }
            if (n == 0) { S_l[w][px] = s; N_l[w][px] = nn; }
        }
    }
    __syncthreads();

    // ---- final merge: 8 wave-partials + global proto, divide, store ----
    if (t < 64) {
        float gdv = gd_s[t];
        float eg = __expf(gdv - 1.1f);           // global proto, exactly once
        float S = eg, N = eg * gdv;
#pragma unroll
        for (int i = 0; i < 8; ++i) { S += S_l[i][t]; N += N_l[i][t]; }
        out[(size_t)b * HWW + px0 + t] = N / S;
    }

#undef QLOADN
#undef LOADB
#undef SPLITW
}

extern "C" void kernel_launch(void* const* d_in, const int* in_sizes, int n_in,
                              void* d_out, int out_size, void* d_ws, size_t ws_size,
                              hipStream_t stream) {
    const float* qry = (const float*)d_in[0];
    const float* sup = (const float*)d_in[1];
    const float* msk = (const float*)d_in[2];
    const float* bg  = (const float*)d_in[3];
    float* out = (float*)d_out;

    float* ws = (float*)d_ws;
    float* protos  = ws;                                   // [B][257][256] f32
    float* validf  = protos + (size_t)BB * PPAD * CC;      // [B][257]
    float* masksum = validf + (size_t)BB * PPAD;           // [B]
    unsigned short* Bimg = (unsigned short*)(masksum + BB); // [B][8][2][256][32] ushorts

    hipLaunchKernelGGL(k01, dim3(BB * CC + BB), dim3(256), 0, stream,
                       sup, msk, bg, protos, validf, masksum);
    hipLaunchKernelGGL(k2_norm, dim3(BB * PPAD), dim3(256), 0, stream, protos, masksum, Bimg);
    hipLaunchKernelGGL(k3_mfma, dim3(BB * (HWW / 64)), dim3(512), 0, stream,
                       qry, Bimg, protos, validf, out);
}